// Round 1
// baseline (16.080 us; speedup 1.0000x reference)
//
#include <hip/hip_runtime.h>

// LinearLUT: out[b,o] = bias[o] + sum_{c<64} dot(basis(b, t=o*64+c), weight[t])
// basis(b,t)[j] = prod_{i<6} (1 + s_i(j)*x[b, mask[t*6+i]])/2, s_i = +-1 per bit i of j.
// Computed via bitwise tensor contraction of the weight row (126 FMAs), no basis
// materialization. wave(64) == tables-per-output(64): lane c handles table o*64+c,
// wave shfl-reduces to one (b,o) scalar.

#define BATCH   256
#define IN_F    64
#define OUT_F   64
#define KBITS   6
#define KK      64
#define TABLES  4096
#define BPB     16   // batch rows per block
#define BPW     4    // batch rows per wave (block has 4 waves)

__global__ __launch_bounds__(256)
void linear_lut_kernel(const float* __restrict__ x,
                       const int*   __restrict__ mask,
                       const float* __restrict__ weight,
                       const float* __restrict__ bias,
                       float*       __restrict__ out)
{
    const int o    = blockIdx.x & (OUT_F - 1);   // output column
    const int bg   = blockIdx.x >> 6;            // batch group [0, BATCH/BPB)
    const int lane = threadIdx.x & 63;
    const int wave = threadIdx.x >> 6;
    const int t    = o * 64 + lane;              // this lane's table

    // Stage this block's 16 x-rows into LDS (4 KiB), one float4 per thread.
    __shared__ float xs[BPB][IN_F];
    {
        const float4* src = reinterpret_cast<const float4*>(x + bg * BPB * IN_F);
        float4*       dst = reinterpret_cast<float4*>(&xs[0][0]);
        dst[threadIdx.x] = src[threadIdx.x];
    }

    // Per-lane table constants: 6 mask indices + 64-entry weight row (registers).
    int m[KBITS];
#pragma unroll
    for (int i = 0; i < KBITS; ++i) m[i] = mask[t * KBITS + i];

    float w[KK];
    {
        const float4* wp = reinterpret_cast<const float4*>(weight + (size_t)t * KK);
#pragma unroll
        for (int i = 0; i < KK / 4; ++i) {
            float4 v = wp[i];
            w[4 * i + 0] = v.x; w[4 * i + 1] = v.y;
            w[4 * i + 2] = v.z; w[4 * i + 3] = v.w;
        }
    }

    const float bo = bias[o];
    __syncthreads();

    for (int rep = 0; rep < BPW; ++rep) {
        const int bl = wave * BPW + rep;         // local batch row in [0, BPB)

        // Gather the 6 x values and form the pair factors.
        float g0[KBITS], g1[KBITS];
#pragma unroll
        for (int i = 0; i < KBITS; ++i) {
            const float xi = xs[bl][m[i]];
            g0[i] = 0.5f * (1.0f - xi);
            g1[i] = 0.5f * (1.0f + xi);
        }

        // Contract weight over bit 5 down to bit 0: 126 FMAs.
        float v[32];
#pragma unroll
        for (int j = 0; j < 32; ++j) v[j] = w[j] * g0[5] + w[j + 32] * g1[5];
#pragma unroll
        for (int j = 0; j < 16; ++j) v[j] = v[j] * g0[4] + v[j + 16] * g1[4];
#pragma unroll
        for (int j = 0; j < 8;  ++j) v[j] = v[j] * g0[3] + v[j + 8]  * g1[3];
#pragma unroll
        for (int j = 0; j < 4;  ++j) v[j] = v[j] * g0[2] + v[j + 4]  * g1[2];
#pragma unroll
        for (int j = 0; j < 2;  ++j) v[j] = v[j] * g0[1] + v[j + 2]  * g1[1];
        float acc = v[0] * g0[0] + v[1] * g1[0];

        // Wave-wide sum over the 64 tables of this output column.
#pragma unroll
        for (int off = 32; off > 0; off >>= 1)
            acc += __shfl_xor(acc, off, 64);

        if (lane == 0) {
            const int b = bg * BPB + bl;
            out[b * OUT_F + o] = acc + bo;
        }
    }
}

extern "C" void kernel_launch(void* const* d_in, const int* in_sizes, int n_in,
                              void* d_out, int out_size, void* d_ws, size_t ws_size,
                              hipStream_t stream)
{
    const float* x      = (const float*)d_in[0];
    const int*   mask   = (const int*)  d_in[1];
    const float* weight = (const float*)d_in[2];
    const float* bias   = (const float*)d_in[3];
    float*       out    = (float*)d_out;

    const int grid = (BATCH / BPB) * OUT_F;  // 1024 blocks
    linear_lut_kernel<<<grid, 256, 0, stream>>>(x, mask, weight, bias, out);
}

// Round 2
// 12.915 us; speedup vs baseline: 1.2451x; 1.2451x over previous
//
#include <hip/hip_runtime.h>

// LinearLUT: out[b,o] = bias[o] + sum_{c<64} dot(basis(b, t=o*64+c), weight[t])
// basis(b,t)[j] = prod_{i<6} (1 + s_i(j)*x[b, mask[t*6+i]])/2, s_i = +-1 per bit i of j.
// Bitwise tensor contraction of the weight row (126 FMAs/table/row), no basis
// materialization. wave(64) == tables-per-output(64): lane c owns table o*64+c,
// wave shfl-reduces to one (b,o) scalar.
//
// R1: BPW 4->8 (grid 512, 2 blocks/CU) halves redundant weight pulls (64->32 MB);
// acc[8] + deferred butterfly turns 8 serial 6-deep shfl chains into 48
// independent pipelined shfls; mask as 3x int2.

#define BATCH   256
#define IN_F    64
#define OUT_F   64
#define KBITS   6
#define KK      64
#define TABLES  4096
#define BPB     32   // batch rows per block
#define BPW     8    // batch rows per wave (block has 4 waves)

__global__ __launch_bounds__(256)
void linear_lut_kernel(const float* __restrict__ x,
                       const int*   __restrict__ mask,
                       const float* __restrict__ weight,
                       const float* __restrict__ bias,
                       float*       __restrict__ out)
{
    const int o    = blockIdx.x & (OUT_F - 1);   // output column
    const int bg   = blockIdx.x >> 6;            // batch group [0, BATCH/BPB)
    const int lane = threadIdx.x & 63;
    const int wave = threadIdx.x >> 6;
    const int t    = o * 64 + lane;              // this lane's table

    // Stage this block's 32 x-rows into LDS (8 KiB), two float4 per thread.
    __shared__ float xs[BPB][IN_F];
    {
        const float4* src = reinterpret_cast<const float4*>(x + bg * BPB * IN_F);
        float4*       dst = reinterpret_cast<float4*>(&xs[0][0]);
        dst[threadIdx.x]       = src[threadIdx.x];
        dst[threadIdx.x + 256] = src[threadIdx.x + 256];
    }

    // Per-lane table constants: 6 mask indices (3x int2, t*24 is 8B-aligned)
    // + 64-entry weight row in registers.
    int m[KBITS];
    {
        const int2* mp = reinterpret_cast<const int2*>(mask + t * KBITS);
        const int2 a = mp[0], b = mp[1], c = mp[2];
        m[0] = a.x; m[1] = a.y; m[2] = b.x; m[3] = b.y; m[4] = c.x; m[5] = c.y;
    }

    float w[KK];
    {
        const float4* wp = reinterpret_cast<const float4*>(weight + (size_t)t * KK);
#pragma unroll
        for (int i = 0; i < KK / 4; ++i) {
            float4 v = wp[i];
            w[4 * i + 0] = v.x; w[4 * i + 1] = v.y;
            w[4 * i + 2] = v.z; w[4 * i + 3] = v.w;
        }
    }

    const float bo = bias[o];
    __syncthreads();

    float acc[BPW];
#pragma unroll
    for (int rep = 0; rep < BPW; ++rep) {
        const int bl = wave * BPW + rep;         // local batch row in [0, BPB)

        // Gather the 6 x values and form the pair factors.
        float g0[KBITS], g1[KBITS];
#pragma unroll
        for (int i = 0; i < KBITS; ++i) {
            const float xi = xs[bl][m[i]];
            g0[i] = 0.5f - 0.5f * xi;
            g1[i] = 0.5f + 0.5f * xi;
        }

        // Contract weight over bit 5 down to bit 0: 126 FMAs.
        float v[32];
#pragma unroll
        for (int j = 0; j < 32; ++j) v[j] = w[j] * g0[5] + w[j + 32] * g1[5];
#pragma unroll
        for (int j = 0; j < 16; ++j) v[j] = v[j] * g0[4] + v[j + 16] * g1[4];
#pragma unroll
        for (int j = 0; j < 8;  ++j) v[j] = v[j] * g0[3] + v[j + 8]  * g1[3];
#pragma unroll
        for (int j = 0; j < 4;  ++j) v[j] = v[j] * g0[2] + v[j + 4]  * g1[2];
#pragma unroll
        for (int j = 0; j < 2;  ++j) v[j] = v[j] * g0[1] + v[j + 2]  * g1[1];
        acc[rep] = v[0] * g0[0] + v[1] * g1[0];
    }

    // 8 independent 6-level butterflies — pipelined, not serialized per rep.
#pragma unroll
    for (int rep = 0; rep < BPW; ++rep) {
        float a = acc[rep];
#pragma unroll
        for (int off = 32; off > 0; off >>= 1)
            a += __shfl_xor(a, off, 64);
        acc[rep] = a;
    }

    if (lane == 0) {
        const int b0 = bg * BPB + wave * BPW;
#pragma unroll
        for (int rep = 0; rep < BPW; ++rep)
            out[(b0 + rep) * OUT_F + o] = acc[rep] + bo;
    }
}

extern "C" void kernel_launch(void* const* d_in, const int* in_sizes, int n_in,
                              void* d_out, int out_size, void* d_ws, size_t ws_size,
                              hipStream_t stream)
{
    const float* x      = (const float*)d_in[0];
    const int*   mask   = (const int*)  d_in[1];
    const float* weight = (const float*)d_in[2];
    const float* bias   = (const float*)d_in[3];
    float*       out    = (float*)d_out;

    const int grid = (BATCH / BPB) * OUT_F;  // 512 blocks, 2/CU
    linear_lut_kernel<<<grid, 256, 0, stream>>>(x, mask, weight, bias, out);
}